// Round 1
// baseline (156.724 us; speedup 1.0000x reference)
//
#include <hip/hip_runtime.h>
#include <stdint.h>

// out = dequant( int8(lhs*ls) @ int8(rhs*rs) ) / (ls*rs), 4096^3, fp32 in/out.
// ls = 127 / max(amax|lhs|, 1e-12). Int core is bit-exact vs numpy (RNE quant).
//
// Workspace: [0,16Mi) qA int8 MxK ; [16Mi,32Mi) qBT int8 NxK ; then 2x u32 amax bits.
//
// GEMM v2: 256x256 tile, 8 waves (2Mx4N), BK=64, 3-deep LDS ring (96 KiB),
// counted s_waitcnt vmcnt(4) + raw s_barrier (loads stay in flight across
// barriers -- T3/T4), s_setprio around the MFMA cluster (T5). Frag reads are
// bank-conflict-free via pre-swizzled global staging source (rule 21 /
// m173): LDS row (64 B = 4 quads) position p holds global quad
// (p - (row>>1)) & 3, so a frag read for quad q hits position
// (q + (row>>1)) & 3 -> each 16-lane ds_read_b128 phase = 2 words/bank.

#define NROW 4096
#define NELEM (4096 * 4096)

typedef __attribute__((ext_vector_type(4))) int int32x4;
typedef const __attribute__((address_space(1))) int8_t* gptr1_t;
typedef __attribute__((address_space(3))) int8_t* lptr3_t;

// One dispatch, both tensors: even blocks -> lhs, odd -> rhs. 1024 blocks per
// tensor; 4 independent partial maxima for ILP (grid covers NELEM/4 float4s in
// exactly 16 strides -> 4 unrolled iterations, no remainder).
__global__ void absmax_both_kernel(const float* __restrict__ lhs,
                                   const float* __restrict__ rhs,
                                   unsigned* __restrict__ amax) {
    __shared__ float red[4];
    const int t = blockIdx.x & 1;
    const float4* x4 = (const float4*)(t ? rhs : lhs);
    const int bid = blockIdx.x >> 1;
    const int stride = (gridDim.x >> 1) * blockDim.x;  // 262144
    int i = bid * blockDim.x + threadIdx.x;
    float m0 = 0.0f, m1 = 0.0f, m2 = 0.0f, m3 = 0.0f;
    for (; i + 3 * stride < NELEM / 4; i += 4 * stride) {
        float4 a = x4[i];
        float4 b = x4[i + stride];
        float4 c = x4[i + 2 * stride];
        float4 d = x4[i + 3 * stride];
        m0 = fmaxf(m0, fmaxf(fmaxf(fabsf(a.x), fabsf(a.y)),
                             fmaxf(fabsf(a.z), fabsf(a.w))));
        m1 = fmaxf(m1, fmaxf(fmaxf(fabsf(b.x), fabsf(b.y)),
                             fmaxf(fabsf(b.z), fabsf(b.w))));
        m2 = fmaxf(m2, fmaxf(fmaxf(fabsf(c.x), fabsf(c.y)),
                             fmaxf(fabsf(c.z), fabsf(c.w))));
        m3 = fmaxf(m3, fmaxf(fmaxf(fabsf(d.x), fabsf(d.y)),
                             fmaxf(fabsf(d.z), fabsf(d.w))));
    }
    for (; i < NELEM / 4; i += stride) {
        float4 a = x4[i];
        m0 = fmaxf(m0, fmaxf(fmaxf(fabsf(a.x), fabsf(a.y)),
                             fmaxf(fabsf(a.z), fabsf(a.w))));
    }
    float m = fmaxf(fmaxf(m0, m1), fmaxf(m2, m3));
    for (int off = 32; off > 0; off >>= 1)
        m = fmaxf(m, __shfl_down(m, off, 64));
    const int lane = threadIdx.x & 63, wave = threadIdx.x >> 6;
    if (lane == 0) red[wave] = m;
    __syncthreads();
    if (threadIdx.x == 0) {
        float b = fmaxf(fmaxf(red[0], red[1]), fmaxf(red[2], red[3]));
        atomicMax(amax + t, __float_as_uint(b));  // |x|>=0: bits monotone as uint
    }
}

__device__ __forceinline__ int q8(float v, float s) {
    int r = __float2int_rn(v * s);  // RNE, matches jnp.round
    r = r < -127 ? -127 : r;
    r = r > 127 ? 127 : r;
    return r;
}

// Fused quantization: blocks [0,16384) quantize A straight; blocks
// [16384, 20480) quantize+transpose B via a 64x64 LDS tile.
__global__ void quant_kernel(const float* __restrict__ lhs,
                             const float* __restrict__ rhs,
                             int8_t* __restrict__ qA, int8_t* __restrict__ qT,
                             const unsigned* __restrict__ amax) {
    __shared__ int8_t sm[64][68];
    if (blockIdx.x < 16384) {
        const float s = 127.0f / fmaxf(__uint_as_float(amax[0]), 1e-12f);
        const int i = blockIdx.x * blockDim.x + threadIdx.x;
        float4 v = ((const float4*)lhs)[i];
        int b0 = q8(v.x, s), b1 = q8(v.y, s), b2 = q8(v.z, s), b3 = q8(v.w, s);
        ((int*)qA)[i] = (b0 & 0xff) | ((b1 & 0xff) << 8) | ((b2 & 0xff) << 16)
                      | ((b3 & 0xff) << 24);
    } else {
        const float s = 127.0f / fmaxf(__uint_as_float(amax[1]), 1e-12f);
        const int b = blockIdx.x - 16384;
        const int n0 = (b & 63) * 64, k0 = (b >> 6) * 64;
        const int rl = threadIdx.x >> 4;   // k row within 16-row slab
        const int nq = threadIdx.x & 15;   // float4 column
        for (int r = 0; r < 4; ++r) {
            const int kl = r * 16 + rl;
            float4 v = *(const float4*)(rhs + (size_t)(k0 + kl) * NROW + n0 + nq * 4);
            sm[nq * 4 + 0][kl] = (int8_t)q8(v.x, s);
            sm[nq * 4 + 1][kl] = (int8_t)q8(v.y, s);
            sm[nq * 4 + 2][kl] = (int8_t)q8(v.z, s);
            sm[nq * 4 + 3][kl] = (int8_t)q8(v.w, s);
        }
        __syncthreads();
        const int nl = threadIdx.x >> 2;
        const int kq = threadIdx.x & 3;
        int4 w;
        w.x = *(const int*)&sm[nl][kq * 16 + 0];
        w.y = *(const int*)&sm[nl][kq * 16 + 4];
        w.z = *(const int*)&sm[nl][kq * 16 + 8];
        w.w = *(const int*)&sm[nl][kq * 16 + 12];
        *(int4*)(qT + (size_t)(n0 + nl) * NROW + k0 + kq * 16) = w;
    }
}

// 256x256 tile, 8 waves, BK=64, 3-buffer LDS ring, counted vmcnt.
// Ring invariant at iteration kt: compute reads slot kt%3; stage(kt+2) writes
// slot (kt+2)%3, whose last readers finished at the barrier ending iteration
// kt-1. End-of-iteration vmcnt(4) retires exactly tile kt+1's 4 loads while
// tile kt+2's 4 remain in flight across the raw s_barrier.
__global__ __launch_bounds__(512, 2) void gemm_i8_kernel(
    const int8_t* __restrict__ qA, const int8_t* __restrict__ qBT,
    float* __restrict__ out, const unsigned* __restrict__ amax) {
    __shared__ __align__(16) int8_t sA[3][256 * 64];
    __shared__ __align__(16) int8_t sB[3][256 * 64];

    const int tid = threadIdx.x;
    const int lane = tid & 63;
    const int wave = tid >> 6;      // 0..7
    const int wm = wave >> 2;       // 0..1 : 128-row sub-tile
    const int wn = wave & 3;        // 0..3 : 64-col sub-tile
    const int m0 = blockIdx.y * 256, n0 = blockIdx.x * 256;

    const int r = lane & 15;        // row/col within 16
    const int q = lane >> 4;        // K-quad (16 B) within 64

    // ds-read byte offsets within a tile slot (pos independent of mi/ni:
    // (row + 16*mi)>>1 changes by 8*mi, which is 0 mod 4 -> fold mi into the
    // ds_read immediate offset, 8 reads share one address register).
    const int rowA = wm * 128 + r;
    const int aoff = rowA * 64 + ((q + (rowA >> 1)) & 3) * 16;
    const int rowB = wn * 64 + r;
    const int boff = rowB * 64 + ((q + (rowB >> 1)) & 3) * 16;

    // Staging: 1024 16B-chunks per tensor per K-tile, 2 per thread. Linear
    // LDS destination (global_load_lds requirement); global source quad is
    // inverse-swizzled: chunk C -> row C>>2, pos C&3 holds quad (pos-row>>1)&3.
    const int C0 = tid, C1 = tid + 512;
    const int rS0 = C0 >> 2, G0 = ((C0 & 3) - (rS0 >> 1)) & 3;
    const int rS1 = C1 >> 2, G1 = ((C1 & 3) - (rS1 >> 1)) & 3;
    const gptr1_t pA0 = (gptr1_t)(qA + (size_t)(m0 + rS0) * NROW + G0 * 16);
    const gptr1_t pA1 = (gptr1_t)(qA + (size_t)(m0 + rS1) * NROW + G1 * 16);
    const gptr1_t pB0 = (gptr1_t)(qBT + (size_t)(n0 + rS0) * NROW + G0 * 16);
    const gptr1_t pB1 = (gptr1_t)(qBT + (size_t)(n0 + rS1) * NROW + G1 * 16);
    int8_t* sAf = &sA[0][0];
    int8_t* sBf = &sB[0][0];
    const int d0 = C0 * 16, d1 = C1 * 16;

    int32x4 acc[8][4];
#pragma unroll
    for (int mi = 0; mi < 8; ++mi)
#pragma unroll
        for (int ni = 0; ni < 4; ++ni) acc[mi][ni] = (int32x4)(0);

    auto stage = [&](int buf, int kt) {
        const int kb = kt * 64;
        __builtin_amdgcn_global_load_lds(pA0 + kb, (lptr3_t)(sAf + buf * 16384 + d0), 16, 0, 0);
        __builtin_amdgcn_global_load_lds(pA1 + kb, (lptr3_t)(sAf + buf * 16384 + d1), 16, 0, 0);
        __builtin_amdgcn_global_load_lds(pB0 + kb, (lptr3_t)(sBf + buf * 16384 + d0), 16, 0, 0);
        __builtin_amdgcn_global_load_lds(pB1 + kb, (lptr3_t)(sBf + buf * 16384 + d1), 16, 0, 0);
    };

    auto compute = [&](int cur) {
        const int8_t* a = sAf + cur * 16384;
        const int8_t* b = sBf + cur * 16384;
        int32x4 af[8], bf[4];
#pragma unroll
        for (int mi = 0; mi < 8; ++mi)
            af[mi] = *(const int32x4*)(a + aoff + mi * 1024);
#pragma unroll
        for (int ni = 0; ni < 4; ++ni)
            bf[ni] = *(const int32x4*)(b + boff + ni * 1024);
        __builtin_amdgcn_s_setprio(1);
#pragma unroll
        for (int mi = 0; mi < 8; ++mi)
#pragma unroll
            for (int ni = 0; ni < 4; ++ni)
                acc[mi][ni] = __builtin_amdgcn_mfma_i32_16x16x64_i8(
                    af[mi], bf[ni], acc[mi][ni], 0, 0, 0);
        __builtin_amdgcn_s_setprio(0);
    };

    // Prologue: fill slots 0,1; retire tile 0 (4 oldest loads), keep tile 1
    // in flight.
    stage(0, 0);
    stage(1, 1);
    asm volatile("s_waitcnt vmcnt(4)" ::: "memory");
    __builtin_amdgcn_s_barrier();
    __builtin_amdgcn_sched_barrier(0);

    int cur = 0, stg = 2;
#pragma unroll 1
    for (int kt = 0; kt < 62; ++kt) {
        stage(stg, kt + 2);
        compute(cur);
        asm volatile("s_waitcnt vmcnt(4)" ::: "memory");  // retire tile kt+1
        __builtin_amdgcn_s_barrier();
        __builtin_amdgcn_sched_barrier(0);
        cur = (cur == 2) ? 0 : cur + 1;
        stg = (stg == 2) ? 0 : stg + 1;
    }
    compute(cur);  // kt = 62
    asm volatile("s_waitcnt vmcnt(0)" ::: "memory");      // retire tile 63
    __builtin_amdgcn_s_barrier();
    __builtin_amdgcn_sched_barrier(0);
    cur = (cur == 2) ? 0 : cur + 1;
    compute(cur);  // kt = 63

    // Epilogue: dequant + store. C/D layout: col = lane&15, row = (lane>>4)*4+reg
    const float ls = 127.0f / fmaxf(__uint_as_float(amax[0]), 1e-12f);
    const float rs = 127.0f / fmaxf(__uint_as_float(amax[1]), 1e-12f);
    const float inv = 1.0f / (ls * rs);
#pragma unroll
    for (int mi = 0; mi < 8; ++mi)
#pragma unroll
        for (int ni = 0; ni < 4; ++ni)
#pragma unroll
            for (int reg = 0; reg < 4; ++reg) {
                const int row = m0 + wm * 128 + mi * 16 + q * 4 + reg;
                const int col = n0 + wn * 64 + ni * 16 + r;
                out[(size_t)row * NROW + col] = (float)acc[mi][ni][reg] * inv;
            }
}

extern "C" void kernel_launch(void* const* d_in, const int* in_sizes, int n_in,
                              void* d_out, int out_size, void* d_ws,
                              size_t ws_size, hipStream_t stream) {
    const float* lhs = (const float*)d_in[0];
    const float* rhs = (const float*)d_in[1];
    float* out = (float*)d_out;

    int8_t* qA = (int8_t*)d_ws;
    int8_t* qBT = qA + (size_t)16 * 1024 * 1024;
    unsigned* amax = (unsigned*)(qBT + (size_t)16 * 1024 * 1024);

    hipMemsetAsync(amax, 0, 8, stream);
    absmax_both_kernel<<<2048, 256, 0, stream>>>(lhs, rhs, amax);
    quant_kernel<<<16384 + 4096, 256, 0, stream>>>(lhs, rhs, qA, qBT, amax);
    gemm_i8_kernel<<<dim3(16, 16), 512, 0, stream>>>(qA, qBT, out, amax);
}